// Round 1
// baseline (375.174 us; speedup 1.0000x reference)
//
#include <hip/hip_runtime.h>
#include <hip/hip_bf16.h>
#include <math.h>

#define N_NODES 22
#define T_DIM   500
#define TP      512          // padded T
#define KHOP    3
#define KK      (KHOP*TP)    // 1536 padded K

typedef __bf16 v8bf __attribute__((ext_vector_type(8)));
typedef float  v4f  __attribute__((ext_vector_type(4)));

// ---------------- 1) softmax(adj) and A^2 (tiny) ----------------
__global__ __launch_bounds__(512) void prep_adj(const float* __restrict__ adj,
                                                float* __restrict__ A1,
                                                float* __restrict__ A2) {
    __shared__ float As[N_NODES][N_NODES];
    int tid = threadIdx.x;
    if (tid < N_NODES) {
        float row[N_NODES];
        float m = -1e30f;
        for (int j = 0; j < N_NODES; ++j) { row[j] = adj[tid*N_NODES + j]; m = fmaxf(m, row[j]); }
        float s = 0.f;
        for (int j = 0; j < N_NODES; ++j) { row[j] = expf(row[j] - m); s += row[j]; }
        float inv = 1.f / s;
        for (int j = 0; j < N_NODES; ++j) { float v = row[j]*inv; As[tid][j] = v; A1[tid*N_NODES + j] = v; }
    }
    __syncthreads();
    if (tid < N_NODES*N_NODES) {
        int n = tid / N_NODES, mm = tid - (tid / N_NODES)*N_NODES;
        float s = 0.f;
        for (int k = 0; k < N_NODES; ++k) s += As[n][k] * As[k][mm];
        A2[tid] = s;
    }
}

// ---------------- 2) W -> Wt bf16, transposed+padded: Wt[o][k*512+t] = W[k][t][o] ----------------
__global__ __launch_bounds__(TP) void prep_W(const float* __restrict__ W,
                                             __hip_bfloat16* __restrict__ Wt) {
    int bx = blockIdx.x;
    int k = bx >> 9, o = bx & 511;
    int t = threadIdx.x;
    float v = 0.f;
    if (o < T_DIM && t < T_DIM) v = W[(size_t)k*T_DIM*T_DIM + (size_t)t*T_DIM + o];
    Wt[(size_t)o*KK + k*TP + t] = __float2bfloat16(v);
}

// ---------------- 3) H = [x ; A x ; A^2 x] bf16, K-padded ----------------
__global__ __launch_bounds__(256) void prep_H(const float* __restrict__ x,
                                              const float* __restrict__ A1,
                                              const float* __restrict__ A2,
                                              __hip_bfloat16* __restrict__ Hb) {
    __shared__ float xs[N_NODES][TP];
    __shared__ float A1s[N_NODES*N_NODES];
    __shared__ float A2s[N_NODES*N_NODES];
    int b = blockIdx.x, tid = threadIdx.x;
    for (int idx = tid; idx < N_NODES*TP; idx += 256) {
        int n = idx >> 9, t = idx & 511;
        xs[n][t] = (t < T_DIM) ? x[((size_t)b*N_NODES + n)*T_DIM + t] : 0.f;
    }
    for (int idx = tid; idx < N_NODES*N_NODES; idx += 256) { A1s[idx] = A1[idx]; A2s[idx] = A2[idx]; }
    __syncthreads();
    for (int t = tid; t < TP; t += 256) {
        for (int n = 0; n < N_NODES; ++n) {
            float h0 = xs[n][t];
            float h1 = 0.f, h2 = 0.f;
            for (int m = 0; m < N_NODES; ++m) {
                float xv = xs[m][t];
                h1 = fmaf(A1s[n*N_NODES + m], xv, h1);
                h2 = fmaf(A2s[n*N_NODES + m], xv, h2);
            }
            size_t base = ((size_t)b*N_NODES + n)*KK + t;
            Hb[base]        = __float2bfloat16(h0);
            Hb[base + TP]   = __float2bfloat16(h1);
            Hb[base + 2*TP] = __float2bfloat16(h2);
        }
    }
}

// ---------------- 4) MFMA GEMM + fused 40x broadcast epilogue ----------------
// out[row = b*22+n][col = o] = sum_K Hb[row][K] * Wt[col][K]  (+ bias), tiled E times.
#define BM 64
#define BN 128
#define BK 64

__global__ __launch_bounds__(256) void gemm_bcast(const __hip_bfloat16* __restrict__ Hb,
                                                  const __hip_bfloat16* __restrict__ Wt,
                                                  const float* __restrict__ bias,
                                                  float* __restrict__ out, int E) {
    __shared__ __hip_bfloat16 sA[BM*BK];   // 8 KB, XOR-swizzled at 16B-chunk level
    __shared__ __hip_bfloat16 sB[BN*BK];   // 16 KB, XOR-swizzled
    const int tid  = threadIdx.x;
    const int bn   = blockIdx.x;           // 0..3   (cols of 128)
    const int bm   = blockIdx.y;           // 0..87  (rows of 64)
    const int lane = tid & 63, wid = tid >> 6;
    const int wr = wid >> 1, wc = wid & 1; // wave -> 32-row x 64-col sub-tile

    v4f acc[2][4];
#pragma unroll
    for (int m = 0; m < 2; ++m)
#pragma unroll
        for (int n = 0; n < 4; ++n) acc[m][n] = (v4f){0.f, 0.f, 0.f, 0.f};

    const size_t a_base = (size_t)(bm*BM) * KK;
    const size_t b_base = (size_t)(bn*BN) * KK;

    for (int k0 = 0; k0 < KK; k0 += BK) {
        // stage A tile: 64 rows x 8 chunks(16B); chunk c stored at c ^ (row&7)
#pragma unroll
        for (int i = 0; i < 2; ++i) {
            int idx = tid + i*256;
            int row = idx >> 3, c = idx & 7;
            const uint4 v = *(const uint4*)(Hb + a_base + (size_t)row*KK + k0 + c*8);
            *(uint4*)(sA + ((row*8) + (c ^ (row & 7)))*8) = v;
        }
        // stage B tile: 128 rows x 8 chunks
#pragma unroll
        for (int i = 0; i < 4; ++i) {
            int idx = tid + i*256;
            int row = idx >> 3, c = idx & 7;
            const uint4 v = *(const uint4*)(Wt + b_base + (size_t)row*KK + k0 + c*8);
            *(uint4*)(sB + ((row*8) + (c ^ (row & 7)))*8) = v;
        }
        __syncthreads();
#pragma unroll
        for (int ks = 0; ks < 2; ++ks) {
            v8bf af[2], bfr[4];
#pragma unroll
            for (int m = 0; m < 2; ++m) {
                int row = wr*32 + m*16 + (lane & 15);
                int c   = ks*4 + (lane >> 4);
                af[m] = *(const v8bf*)(sA + (row*8 + (c ^ (row & 7)))*8);
            }
#pragma unroll
            for (int n = 0; n < 4; ++n) {
                int row = wc*64 + n*16 + (lane & 15);
                int c   = ks*4 + (lane >> 4);
                bfr[n] = *(const v8bf*)(sB + (row*8 + (c ^ (row & 7)))*8);
            }
#pragma unroll
            for (int m = 0; m < 2; ++m)
#pragma unroll
                for (int n = 0; n < 4; ++n)
                    acc[m][n] = __builtin_amdgcn_mfma_f32_16x16x32_bf16(af[m], bfr[n], acc[m][n], 0, 0, 0);
        }
        __syncthreads();
    }

    // epilogue: C/D layout col=lane&15, row=(lane>>4)*4+r  [m89-verified]
    const int row0 = bm*BM + wr*32;
    const int col0 = bn*BN + wc*64;
#pragma unroll
    for (int n = 0; n < 4; ++n) {
        int col = col0 + n*16 + (lane & 15);
        if (col >= T_DIM) continue;
        float bv = bias[col];
#pragma unroll
        for (int m = 0; m < 2; ++m) {
            int rowb = row0 + m*16 + ((lane >> 4) << 2);
#pragma unroll
            for (int r = 0; r < 4; ++r) {
                int row  = rowb + r;
                int bidx = row / N_NODES;
                int node = row - bidx*N_NODES;
                float v  = acc[m][n][r] + bv;
                size_t base = ((size_t)bidx*E*N_NODES + node)*T_DIM + col;
                for (int e = 0; e < E; ++e) { out[base] = v; base += (size_t)N_NODES*T_DIM; }
            }
        }
    }
}

extern "C" void kernel_launch(void* const* d_in, const int* in_sizes, int n_in,
                              void* d_out, int out_size, void* d_ws, size_t ws_size,
                              hipStream_t stream) {
    const float* x    = (const float*)d_in[0];
    const float* adj  = (const float*)d_in[1];
    const float* W    = (const float*)d_in[2];
    const float* bias = (const float*)d_in[3];
    const int B = in_sizes[0] / (N_NODES * T_DIM);            // 256
    const int E = out_size / (B * N_NODES * T_DIM);           // 40

    char* ws = (char*)d_ws;
    float* A1 = (float*)ws;                                   // 484 floats
    float* A2 = A1 + 512;
    __hip_bfloat16* Wt = (__hip_bfloat16*)(ws + 4096);                          // 512*1536 bf16 = 1.5 MB
    __hip_bfloat16* Hb = (__hip_bfloat16*)(ws + 4096 + (size_t)TP*KK*2);        // 5632*1536 bf16 = 16.5 MB
    float* out = (float*)d_out;

    prep_adj<<<1, 512, 0, stream>>>(adj, A1, A2);
    prep_W<<<KHOP*TP, TP, 0, stream>>>(W, Wt);
    prep_H<<<B, 256, 0, stream>>>(x, A1, A2, Hb);
    dim3 grid(4, (B*N_NODES)/BM);   // (4, 88) = 352 blocks
    gemm_bcast<<<grid, 256, 0, stream>>>(Hb, Wt, bias, out, E);
}

// Round 2
// 170.387 us; speedup vs baseline: 2.2019x; 2.2019x over previous
//
#include <hip/hip_runtime.h>
#include <hip/hip_bf16.h>
#include <math.h>

#define N_NODES 22
#define T_DIM   500
#define TP      512          // padded T
#define KHOP    3
#define KK      (KHOP*TP)    // 1536 padded K
#define SLICE   (N_NODES*T_DIM)       // 11000 floats = 44000 B per (b,e) slice
#define SLICE4  (SLICE/4)             // 2750 float4

typedef __bf16 v8bf __attribute__((ext_vector_type(8)));
typedef float  v4f  __attribute__((ext_vector_type(4)));

// ---------------- 1) softmax(adj) and A^2 (tiny) ----------------
__global__ __launch_bounds__(512) void prep_adj(const float* __restrict__ adj,
                                                float* __restrict__ A1,
                                                float* __restrict__ A2) {
    __shared__ float As[N_NODES][N_NODES];
    int tid = threadIdx.x;
    if (tid < N_NODES) {
        float row[N_NODES];
        float m = -1e30f;
        for (int j = 0; j < N_NODES; ++j) { row[j] = adj[tid*N_NODES + j]; m = fmaxf(m, row[j]); }
        float s = 0.f;
        for (int j = 0; j < N_NODES; ++j) { row[j] = expf(row[j] - m); s += row[j]; }
        float inv = 1.f / s;
        for (int j = 0; j < N_NODES; ++j) { float v = row[j]*inv; As[tid][j] = v; A1[tid*N_NODES + j] = v; }
    }
    __syncthreads();
    if (tid < N_NODES*N_NODES) {
        int n = tid / N_NODES, mm = tid - (tid / N_NODES)*N_NODES;
        float s = 0.f;
        for (int k = 0; k < N_NODES; ++k) s += As[n][k] * As[k][mm];
        A2[tid] = s;
    }
}

// ---------------- 2) W -> Wt bf16, transposed+padded: Wt[o][k*512+t] = W[k][t][o] ----------------
__global__ __launch_bounds__(TP) void prep_W(const float* __restrict__ W,
                                             __hip_bfloat16* __restrict__ Wt) {
    int bx = blockIdx.x;
    int k = bx >> 9, o = bx & 511;
    int t = threadIdx.x;
    float v = 0.f;
    if (o < T_DIM && t < T_DIM) v = W[(size_t)k*T_DIM*T_DIM + (size_t)t*T_DIM + o];
    Wt[(size_t)o*KK + k*TP + t] = __float2bfloat16(v);
}

// ---------------- 3) H = [x ; A x ; A^2 x] bf16, K-padded ----------------
__global__ __launch_bounds__(256) void prep_H(const float* __restrict__ x,
                                              const float* __restrict__ A1,
                                              const float* __restrict__ A2,
                                              __hip_bfloat16* __restrict__ Hb) {
    __shared__ float xs[N_NODES][TP];
    __shared__ float A1s[N_NODES*N_NODES];
    __shared__ float A2s[N_NODES*N_NODES];
    int b = blockIdx.x, tid = threadIdx.x;
    for (int idx = tid; idx < N_NODES*TP; idx += 256) {
        int n = idx >> 9, t = idx & 511;
        xs[n][t] = (t < T_DIM) ? x[((size_t)b*N_NODES + n)*T_DIM + t] : 0.f;
    }
    for (int idx = tid; idx < N_NODES*N_NODES; idx += 256) { A1s[idx] = A1[idx]; A2s[idx] = A2[idx]; }
    __syncthreads();
    for (int t = tid; t < TP; t += 256) {
        for (int n = 0; n < N_NODES; ++n) {
            float h0 = xs[n][t];
            float h1 = 0.f, h2 = 0.f;
            for (int m = 0; m < N_NODES; ++m) {
                float xv = xs[m][t];
                h1 = fmaf(A1s[n*N_NODES + m], xv, h1);
                h2 = fmaf(A2s[n*N_NODES + m], xv, h2);
            }
            size_t base = ((size_t)b*N_NODES + n)*KK + t;
            Hb[base]        = __float2bfloat16(h0);
            Hb[base + TP]   = __float2bfloat16(h1);
            Hb[base + 2*TP] = __float2bfloat16(h2);
        }
    }
}

// ---------------- 4) MFMA GEMM, writes ONLY the e=0 slice of out ----------------
#define BM 64
#define BN 128
#define BK 64

__global__ __launch_bounds__(256) void gemm_compact(const __hip_bfloat16* __restrict__ Hb,
                                                    const __hip_bfloat16* __restrict__ Wt,
                                                    const float* __restrict__ bias,
                                                    float* __restrict__ out, int E) {
    __shared__ __hip_bfloat16 sA[BM*BK];   // 8 KB, XOR-swizzled at 16B-chunk level
    __shared__ __hip_bfloat16 sB[BN*BK];   // 16 KB
    const int tid  = threadIdx.x;
    const int bn   = blockIdx.x;           // 0..3
    const int bm   = blockIdx.y;           // 0..87
    const int lane = tid & 63, wid = tid >> 6;
    const int wr = wid >> 1, wc = wid & 1;

    v4f acc[2][4];
#pragma unroll
    for (int m = 0; m < 2; ++m)
#pragma unroll
        for (int n = 0; n < 4; ++n) acc[m][n] = (v4f){0.f, 0.f, 0.f, 0.f};

    const size_t a_base = (size_t)(bm*BM) * KK;
    const size_t b_base = (size_t)(bn*BN) * KK;

    for (int k0 = 0; k0 < KK; k0 += BK) {
#pragma unroll
        for (int i = 0; i < 2; ++i) {
            int idx = tid + i*256;
            int row = idx >> 3, c = idx & 7;
            const uint4 v = *(const uint4*)(Hb + a_base + (size_t)row*KK + k0 + c*8);
            *(uint4*)(sA + ((row*8) + (c ^ (row & 7)))*8) = v;
        }
#pragma unroll
        for (int i = 0; i < 4; ++i) {
            int idx = tid + i*256;
            int row = idx >> 3, c = idx & 7;
            const uint4 v = *(const uint4*)(Wt + b_base + (size_t)row*KK + k0 + c*8);
            *(uint4*)(sB + ((row*8) + (c ^ (row & 7)))*8) = v;
        }
        __syncthreads();
#pragma unroll
        for (int ks = 0; ks < 2; ++ks) {
            v8bf af[2], bfr[4];
#pragma unroll
            for (int m = 0; m < 2; ++m) {
                int row = wr*32 + m*16 + (lane & 15);
                int c   = ks*4 + (lane >> 4);
                af[m] = *(const v8bf*)(sA + (row*8 + (c ^ (row & 7)))*8);
            }
#pragma unroll
            for (int n = 0; n < 4; ++n) {
                int row = wc*64 + n*16 + (lane & 15);
                int c   = ks*4 + (lane >> 4);
                bfr[n] = *(const v8bf*)(sB + (row*8 + (c ^ (row & 7)))*8);
            }
#pragma unroll
            for (int m = 0; m < 2; ++m)
#pragma unroll
                for (int n = 0; n < 4; ++n)
                    acc[m][n] = __builtin_amdgcn_mfma_f32_16x16x32_bf16(af[m], bfr[n], acc[m][n], 0, 0, 0);
        }
        __syncthreads();
    }

    // epilogue: write ONLY e=0 slice. C/D layout col=lane&15, row=(lane>>4)*4+r
    const int row0 = bm*BM + wr*32;
    const int col0 = bn*BN + wc*64;
#pragma unroll
    for (int n = 0; n < 4; ++n) {
        int col = col0 + n*16 + (lane & 15);
        if (col >= T_DIM) continue;
        float bv = bias[col];
#pragma unroll
        for (int m = 0; m < 2; ++m) {
            int rowb = row0 + m*16 + ((lane >> 4) << 2);
#pragma unroll
            for (int r = 0; r < 4; ++r) {
                int row  = rowb + r;
                int bidx = row / N_NODES;
                int node = row - bidx*N_NODES;
                out[((size_t)bidx*E*N_NODES + node)*T_DIM + col] = acc[m][n][r] + bv;
            }
        }
    }
}

// ---------------- 5) broadcast e=0 slice -> e=1..E-1, float4 coalesced ----------------
__global__ __launch_bounds__(256) void bcast(float* __restrict__ out, int E) {
    const int b = blockIdx.x;
    const int e = blockIdx.y + 1;
    const float4* __restrict__ src = (const float4*)(out + (size_t)b*E*SLICE);
    float4*       __restrict__ dst = (float4*)(out + ((size_t)b*E + e)*SLICE);
    for (int i = threadIdx.x; i < SLICE4; i += 256)
        dst[i] = src[i];
}

extern "C" void kernel_launch(void* const* d_in, const int* in_sizes, int n_in,
                              void* d_out, int out_size, void* d_ws, size_t ws_size,
                              hipStream_t stream) {
    const float* x    = (const float*)d_in[0];
    const float* adj  = (const float*)d_in[1];
    const float* W    = (const float*)d_in[2];
    const float* bias = (const float*)d_in[3];
    const int B = in_sizes[0] / (N_NODES * T_DIM);            // 256
    const int E = out_size / (B * N_NODES * T_DIM);           // 40

    char* ws = (char*)d_ws;
    float* A1 = (float*)ws;
    float* A2 = A1 + 512;
    __hip_bfloat16* Wt = (__hip_bfloat16*)(ws + 4096);                     // 1.5 MB
    __hip_bfloat16* Hb = (__hip_bfloat16*)(ws + 4096 + (size_t)TP*KK*2);   // 16.5 MB
    float* out = (float*)d_out;

    prep_adj<<<1, 512, 0, stream>>>(adj, A1, A2);
    prep_W<<<KHOP*TP, TP, 0, stream>>>(W, Wt);
    prep_H<<<B, 256, 0, stream>>>(x, A1, A2, Hb);
    dim3 grid(4, (B*N_NODES)/BM);   // (4, 88) = 352 blocks
    gemm_compact<<<grid, 256, 0, stream>>>(Hb, Wt, bias, out, E);
    if (E > 1) {
        dim3 bg(B, E - 1);          // (256, 39) = 9984 blocks
        bcast<<<bg, 256, 0, stream>>>(out, E);
    }
}